// Round 2
// baseline (224.687 us; speedup 1.0000x reference)
//
#include <hip/hip_runtime.h>
#include <stdint.h>

#define GK 2048
#define GN 2048
#define GM 8192  // tokens = 4 * 2048

typedef int i32x4 __attribute__((ext_vector_type(4)));

// ---------------------------------------------------------------------------
// Stage 1: absmax over x and w (exact, order-independent via atomicMax on bits)
// ---------------------------------------------------------------------------
__global__ __launch_bounds__(256) void absmax_kernel(
    const float4* __restrict__ xv, unsigned nvx,
    const float4* __restrict__ wv, unsigned nvw,
    unsigned* __restrict__ amax)
{
    unsigned i = blockIdx.x * 256u + threadIdx.x;
    const unsigned stride = gridDim.x * 256u;
    const unsigned total = nvx + nvw;
    float mx = 0.f, mw = 0.f;
    for (; i < total; i += stride) {
        if (i < nvx) {
            float4 v = xv[i];
            float a = fmaxf(fmaxf(fabsf(v.x), fabsf(v.y)),
                            fmaxf(fabsf(v.z), fabsf(v.w)));
            mx = fmaxf(mx, a);
        } else {
            float4 v = wv[i - nvx];
            float a = fmaxf(fmaxf(fabsf(v.x), fabsf(v.y)),
                            fmaxf(fabsf(v.z), fabsf(v.w)));
            mw = fmaxf(mw, a);
        }
    }
    #pragma unroll
    for (int off = 32; off > 0; off >>= 1) {
        mx = fmaxf(mx, __shfl_down(mx, off, 64));
        mw = fmaxf(mw, __shfl_down(mw, off, 64));
    }
    __shared__ float smx[4], smw[4];
    const int lane = threadIdx.x & 63, wid = threadIdx.x >> 6;
    if (lane == 0) { smx[wid] = mx; smw[wid] = mw; }
    __syncthreads();
    if (threadIdx.x == 0) {
        mx = fmaxf(fmaxf(smx[0], smx[1]), fmaxf(smx[2], smx[3]));
        mw = fmaxf(fmaxf(smw[0], smw[1]), fmaxf(smw[2], smw[3]));
        atomicMax(&amax[0], __float_as_uint(mx));
        atomicMax(&amax[1], __float_as_uint(mw));
    }
}

// ---------------------------------------------------------------------------
// Stage 2: quantize. Bit-exact vs reference: scale = absmax/127 (IEEE div),
// q = rintf(v/scale) (round-half-even, IEEE div), clip, cast.
// ---------------------------------------------------------------------------
__device__ __forceinline__ signed char quant1(float v, float s) {
    float r = rintf(v / s);
    r = fminf(fmaxf(r, -128.f), 127.f);
    return (signed char)(int)r;
}

__global__ __launch_bounds__(256) void quant_kernel(
    const float4* __restrict__ xv, unsigned nvx,
    const float4* __restrict__ wv, unsigned nvw,
    const unsigned* __restrict__ amax,
    char4* __restrict__ xq, char4* __restrict__ wq)
{
    const float sx = __uint_as_float(amax[0]) / 127.0f;
    const float sw = __uint_as_float(amax[1]) / 127.0f;
    unsigned i = blockIdx.x * 256u + threadIdx.x;
    const unsigned stride = gridDim.x * 256u;
    const unsigned total = nvx + nvw;
    for (; i < total; i += stride) {
        if (i < nvx) {
            float4 v = xv[i];
            char4 q;
            q.x = quant1(v.x, sx); q.y = quant1(v.y, sx);
            q.z = quant1(v.z, sx); q.w = quant1(v.w, sx);
            xq[i] = q;
        } else {
            float4 v = wv[i - nvx];
            char4 q;
            q.x = quant1(v.x, sw); q.y = quant1(v.y, sw);
            q.z = quant1(v.z, sw); q.w = quant1(v.w, sw);
            wq[i - nvx] = q;
        }
    }
}

// ---------------------------------------------------------------------------
// Stage 3: int8 GEMM (m97 structure): 128x128 tile, BK=128, 4 waves (2x2),
// global_load_lds width-16 with pre-swizzled source (slot ^= row&7),
// swizzled ds_read_b128, mfma_i32_16x16x64_i8, fused dequant+bias epilogue.
// A = xq [M,K] row-major; B = wq [N,K] row-major (weight is [out,in] = B^T).
// ---------------------------------------------------------------------------
__global__ __launch_bounds__(256) void gemm_kernel(
    const signed char* __restrict__ Aq,
    const signed char* __restrict__ Bq,
    const float* __restrict__ bias,
    const unsigned* __restrict__ amax,
    float* __restrict__ out)
{
    __shared__ signed char sA[128 * 128];
    __shared__ signed char sB[128 * 128];

    const int tid  = threadIdx.x;
    const int lane = tid & 63;
    const int wid  = tid >> 6;
    const int wr   = wid >> 1;      // wave row 0..1 (64-row strip)
    const int wc   = wid & 1;       // wave col 0..1 (64-col strip)
    const int bn   = blockIdx.x & 15;   // GN/128 = 16
    const int bm   = blockIdx.x >> 4;

    // staging coords: 256 threads x 16B = 4096B per issue (32 rows x 128B)
    const int srow  = tid >> 3;     // 0..31
    const int sslot = tid & 7;      // 0..7 (16B slot within 128B row)

    i32x4 acc[4][4] = {};

    const long Abase = (long)bm * 128 * GK;
    const long Bbase = (long)bn * 128 * GK;

    for (int kt = 0; kt < GK; kt += 128) {
        #pragma unroll
        for (int j = 0; j < 4; ++j) {
            const int row  = j * 32 + srow;
            const int slot = sslot ^ (row & 7);       // pre-swizzled source
            const signed char* src = Aq + Abase + (long)row * GK + kt + slot * 16;
            __builtin_amdgcn_global_load_lds(
                (const __attribute__((address_space(1))) void*)src,
                (__attribute__((address_space(3))) void*)(sA + j * 4096 + wid * 1024),
                16, 0, 0);
        }
        #pragma unroll
        for (int j = 0; j < 4; ++j) {
            const int row  = j * 32 + srow;
            const int slot = sslot ^ (row & 7);
            const signed char* src = Bq + Bbase + (long)row * GK + kt + slot * 16;
            __builtin_amdgcn_global_load_lds(
                (const __attribute__((address_space(1))) void*)src,
                (__attribute__((address_space(3))) void*)(sB + j * 4096 + wid * 1024),
                16, 0, 0);
        }
        __syncthreads();   // drains vmcnt before barrier (compiler-inserted)

        #pragma unroll
        for (int kk = 0; kk < 2; ++kk) {
            i32x4 af[4], bf[4];
            const int g = kk * 4 + (lane >> 4);       // global 16B k-slot 0..7
            #pragma unroll
            for (int m = 0; m < 4; ++m) {
                const int row = wr * 64 + m * 16 + (lane & 15);
                af[m] = *(const i32x4*)(sA + row * 128 + ((g ^ (row & 7)) << 4));
            }
            #pragma unroll
            for (int n = 0; n < 4; ++n) {
                const int row = wc * 64 + n * 16 + (lane & 15);
                bf[n] = *(const i32x4*)(sB + row * 128 + ((g ^ (row & 7)) << 4));
            }
            #pragma unroll
            for (int m = 0; m < 4; ++m)
                #pragma unroll
                for (int n = 0; n < 4; ++n)
                    acc[m][n] = __builtin_amdgcn_mfma_i32_16x16x64_i8(
                        af[m], bf[n], acc[m][n], 0, 0, 0);
        }
        __syncthreads();
    }

    // Epilogue: dequant + bias. C/D layout: col=lane&15, row=(lane>>4)*4+reg.
    const float s = (__uint_as_float(amax[0]) / 127.0f) *
                    (__uint_as_float(amax[1]) / 127.0f);
    const int orow0 = bm * 128 + wr * 64 + (lane >> 4) * 4;
    const int ocol0 = bn * 128 + wc * 64 + (lane & 15);
    #pragma unroll
    for (int n = 0; n < 4; ++n) {
        const int col = ocol0 + n * 16;
        const float bv = bias[col];
        #pragma unroll
        for (int m = 0; m < 4; ++m) {
            const int row = orow0 + m * 16;
            #pragma unroll
            for (int i = 0; i < 4; ++i) {
                out[(long)(row + i) * GN + col] = (float)acc[m][n][i] * s + bv;
            }
        }
    }
}

// ---------------------------------------------------------------------------
extern "C" void kernel_launch(void* const* d_in, const int* in_sizes, int n_in,
                              void* d_out, int out_size, void* d_ws, size_t ws_size,
                              hipStream_t stream) {
    const float* x    = (const float*)d_in[0];
    const float* w    = (const float*)d_in[1];
    const float* bias = (const float*)d_in[2];
    float* out = (float*)d_out;

    // ws layout: [0,256): amax bits (x, w); [256, +16M): xq; then wq (4M).
    const size_t need = 256 + (size_t)GM * GK + (size_t)GN * GK;
    if (ws_size < need) {
        // Scratch too small: bail cleanly (validation will fail and tell us,
        // instead of an OOB write killing the container).
        return;
    }

    unsigned* amax = (unsigned*)d_ws;
    signed char* xq = (signed char*)d_ws + 256;
    signed char* wq = xq + (size_t)GM * GK;

    hipMemsetAsync(d_ws, 0, 8, stream);  // zero amax slots (ws is poisoned 0xAA)

    const unsigned nvx = (unsigned)((size_t)GM * GK / 4);  // float4 count of x
    const unsigned nvw = (unsigned)((size_t)GN * GK / 4);  // float4 count of w

    absmax_kernel<<<2048, 256, 0, stream>>>(
        (const float4*)x, nvx, (const float4*)w, nvw, amax);
    quant_kernel<<<2048, 256, 0, stream>>>(
        (const float4*)x, nvx, (const float4*)w, nvw, amax,
        (char4*)xq, (char4*)wq);
    gemm_kernel<<<(GM / 128) * (GN / 128), 256, 0, stream>>>(
        xq, wq, bias, amax, out);
}

// Round 3
// 180.963 us; speedup vs baseline: 1.2416x; 1.2416x over previous
//
#include <hip/hip_runtime.h>
#include <stdint.h>

#define GK 2048
#define GN 2048
#define GM 8192  // tokens = 4 * 2048

#define NVX (GM * (unsigned)GK / 4)   // 4,194,304 float4 in x
#define NVW (GN * (unsigned)GK / 4)   // 1,048,576 float4 in w

#define XBLK 512   // absmax x-blocks: 4194304/(512*256) = 32 iters exactly
#define WBLK 128   // absmax w-blocks: 1048576/(128*256) = 32 iters exactly
#define QXBLK 4096 // quant x-blocks: 4 float4/thread exactly
#define QWBLK 1024 // quant w-blocks

typedef int i32x4 __attribute__((ext_vector_type(4)));

__device__ __forceinline__ float amax4(float4 v) {
    return fmaxf(fmaxf(fabsf(v.x), fabsf(v.y)), fmaxf(fabsf(v.z), fabsf(v.w)));
}

// ---------------------------------------------------------------------------
// Stage 1: per-block absmax partials (no atomics; ILP-4 loads, no inner branch)
// blocks [0,XBLK): x ; [XBLK, XBLK+WBLK): w. partial[blockIdx] <- block max.
// ---------------------------------------------------------------------------
__global__ __launch_bounds__(256) void absmax_kernel(
    const float4* __restrict__ xv, const float4* __restrict__ wv,
    float* __restrict__ partial)
{
    const bool isx = blockIdx.x < XBLK;
    const float4* __restrict__ src = isx ? xv : wv;
    const unsigned n      = isx ? NVX : NVW;
    const unsigned b0     = isx ? blockIdx.x : blockIdx.x - XBLK;
    const unsigned stride = (isx ? XBLK : WBLK) * 256u;

    unsigned i = b0 * 256u + threadIdx.x;
    float m = 0.f;
    for (; i + 3u * stride < n; i += 4u * stride) {
        float4 a = src[i];
        float4 b = src[i + stride];
        float4 c = src[i + 2u * stride];
        float4 d = src[i + 3u * stride];
        m = fmaxf(m, fmaxf(fmaxf(amax4(a), amax4(b)),
                           fmaxf(amax4(c), amax4(d))));
    }
    for (; i < n; i += stride) m = fmaxf(m, amax4(src[i]));  // safety tail

    #pragma unroll
    for (int off = 32; off > 0; off >>= 1)
        m = fmaxf(m, __shfl_xor(m, off, 64));

    __shared__ float sm[4];
    const int wid = threadIdx.x >> 6;
    if ((threadIdx.x & 63) == 0) sm[wid] = m;
    __syncthreads();
    if (threadIdx.x == 0)
        partial[blockIdx.x] = fmaxf(fmaxf(sm[0], sm[1]), fmaxf(sm[2], sm[3]));
}

// ---------------------------------------------------------------------------
// Stage 1b: single-block reduce of 640 partials -> scales[0]=sx, [1]=sw, [2]=sx*sw
// Numerics identical to reference: scale = absmax / 127.0f (IEEE fp32 div).
// ---------------------------------------------------------------------------
__global__ __launch_bounds__(256) void scale_kernel(
    const float* __restrict__ partial, float* __restrict__ scales)
{
    const int t = threadIdx.x;
    float mx = fmaxf(partial[t], partial[t + 256]);          // covers [0,512)
    float mw = (t < WBLK) ? partial[XBLK + t] : 0.f;         // covers [512,640)
    #pragma unroll
    for (int off = 32; off > 0; off >>= 1) {
        mx = fmaxf(mx, __shfl_xor(mx, off, 64));
        mw = fmaxf(mw, __shfl_xor(mw, off, 64));
    }
    __shared__ float smx[4], smw[4];
    const int wid = t >> 6;
    if ((t & 63) == 0) { smx[wid] = mx; smw[wid] = mw; }
    __syncthreads();
    if (t == 0) {
        float ax = fmaxf(fmaxf(smx[0], smx[1]), fmaxf(smx[2], smx[3]));
        float aw = fmaxf(fmaxf(smw[0], smw[1]), fmaxf(smw[2], smw[3]));
        float sx = ax / 127.0f;
        float sw = aw / 127.0f;
        scales[0] = sx;
        scales[1] = sw;
        scales[2] = sx * sw;
    }
}

// ---------------------------------------------------------------------------
// Stage 2: quantize. Bit-exact vs reference: q = rintf(v / scale) (half-even,
// IEEE div), clip [-128,127], cast. ILP-4, unit-stride loads AND stores.
// ---------------------------------------------------------------------------
__device__ __forceinline__ signed char quant1(float v, float s) {
    float r = rintf(v / s);
    r = fminf(fmaxf(r, -128.f), 127.f);
    return (signed char)(int)r;
}

__device__ __forceinline__ char4 quantv(float4 v, float s) {
    char4 q;
    q.x = quant1(v.x, s); q.y = quant1(v.y, s);
    q.z = quant1(v.z, s); q.w = quant1(v.w, s);
    return q;
}

__global__ __launch_bounds__(256) void quant_kernel(
    const float4* __restrict__ xv, const float4* __restrict__ wv,
    const float* __restrict__ scales,
    char4* __restrict__ xq, char4* __restrict__ wq)
{
    const bool isx = blockIdx.x < QXBLK;
    const float s = isx ? scales[0] : scales[1];
    const float4* __restrict__ src = isx ? xv : wv;
    char4* __restrict__ dst        = isx ? xq : wq;
    const unsigned b0     = isx ? blockIdx.x : blockIdx.x - QXBLK;
    const unsigned stride = (isx ? QXBLK : QWBLK) * 256u;
    const unsigned t      = b0 * 256u + threadIdx.x;

    float4 a = src[t];
    float4 b = src[t + stride];
    float4 c = src[t + 2u * stride];
    float4 d = src[t + 3u * stride];
    dst[t]               = quantv(a, s);
    dst[t + stride]      = quantv(b, s);
    dst[t + 2u * stride] = quantv(c, s);
    dst[t + 3u * stride] = quantv(d, s);
}

// ---------------------------------------------------------------------------
// Stage 3: int8 GEMM (m97 structure): 128x128 tile, BK=128, 4 waves (2x2),
// global_load_lds width-16 with pre-swizzled source (slot ^= row&7),
// swizzled ds_read_b128, mfma_i32_16x16x64_i8, fused dequant+bias epilogue.
// A = xq [M,K] row-major; B = wq [N,K] row-major (weight is [out,in] = B^T).
// ---------------------------------------------------------------------------
__global__ __launch_bounds__(256) void gemm_kernel(
    const signed char* __restrict__ Aq,
    const signed char* __restrict__ Bq,
    const float* __restrict__ bias,
    const float* __restrict__ scales,
    float* __restrict__ out)
{
    __shared__ signed char sA[128 * 128];
    __shared__ signed char sB[128 * 128];

    const int tid  = threadIdx.x;
    const int lane = tid & 63;
    const int wid  = tid >> 6;
    const int wr   = wid >> 1;      // wave row 0..1 (64-row strip)
    const int wc   = wid & 1;       // wave col 0..1 (64-col strip)
    const int bn   = blockIdx.x & 15;   // GN/128 = 16
    const int bm   = blockIdx.x >> 4;

    // staging coords: 256 threads x 16B = 4096B per issue (32 rows x 128B)
    const int srow  = tid >> 3;     // 0..31
    const int sslot = tid & 7;      // 0..7 (16B slot within 128B row)

    i32x4 acc[4][4] = {};

    const long Abase = (long)bm * 128 * GK;
    const long Bbase = (long)bn * 128 * GK;

    for (int kt = 0; kt < GK; kt += 128) {
        #pragma unroll
        for (int j = 0; j < 4; ++j) {
            const int row  = j * 32 + srow;
            const int slot = sslot ^ (row & 7);       // pre-swizzled source
            const signed char* src = Aq + Abase + (long)row * GK + kt + slot * 16;
            __builtin_amdgcn_global_load_lds(
                (const __attribute__((address_space(1))) void*)src,
                (__attribute__((address_space(3))) void*)(sA + j * 4096 + wid * 1024),
                16, 0, 0);
        }
        #pragma unroll
        for (int j = 0; j < 4; ++j) {
            const int row  = j * 32 + srow;
            const int slot = sslot ^ (row & 7);
            const signed char* src = Bq + Bbase + (long)row * GK + kt + slot * 16;
            __builtin_amdgcn_global_load_lds(
                (const __attribute__((address_space(1))) void*)src,
                (__attribute__((address_space(3))) void*)(sB + j * 4096 + wid * 1024),
                16, 0, 0);
        }
        __syncthreads();   // drains vmcnt before barrier (compiler-inserted)

        #pragma unroll
        for (int kk = 0; kk < 2; ++kk) {
            i32x4 af[4], bf[4];
            const int g = kk * 4 + (lane >> 4);       // global 16B k-slot 0..7
            #pragma unroll
            for (int m = 0; m < 4; ++m) {
                const int row = wr * 64 + m * 16 + (lane & 15);
                af[m] = *(const i32x4*)(sA + row * 128 + ((g ^ (row & 7)) << 4));
            }
            #pragma unroll
            for (int n = 0; n < 4; ++n) {
                const int row = wc * 64 + n * 16 + (lane & 15);
                bf[n] = *(const i32x4*)(sB + row * 128 + ((g ^ (row & 7)) << 4));
            }
            #pragma unroll
            for (int m = 0; m < 4; ++m)
                #pragma unroll
                for (int n = 0; n < 4; ++n)
                    acc[m][n] = __builtin_amdgcn_mfma_i32_16x16x64_i8(
                        af[m], bf[n], acc[m][n], 0, 0, 0);
        }
        __syncthreads();
    }

    // Epilogue: dequant + bias. C/D layout: col=lane&15, row=(lane>>4)*4+reg.
    const float s = scales[2];
    const int orow0 = bm * 128 + wr * 64 + (lane >> 4) * 4;
    const int ocol0 = bn * 128 + wc * 64 + (lane & 15);
    #pragma unroll
    for (int n = 0; n < 4; ++n) {
        const int col = ocol0 + n * 16;
        const float bv = bias[col];
        #pragma unroll
        for (int m = 0; m < 4; ++m) {
            const int row = orow0 + m * 16;
            #pragma unroll
            for (int i = 0; i < 4; ++i) {
                out[(long)(row + i) * GN + col] = (float)acc[m][n][i] * s + bv;
            }
        }
    }
}

// ---------------------------------------------------------------------------
extern "C" void kernel_launch(void* const* d_in, const int* in_sizes, int n_in,
                              void* d_out, int out_size, void* d_ws, size_t ws_size,
                              hipStream_t stream) {
    const float* x    = (const float*)d_in[0];
    const float* w    = (const float*)d_in[1];
    const float* bias = (const float*)d_in[2];
    float* out = (float*)d_out;

    // ws layout: [0,16): scales {sx, sw, sx*sw}; [16, 16+640*4): partials;
    // [4096, +16M): xq; then wq (4M). Every slot written before read -> no memset.
    const size_t need = 4096 + (size_t)GM * GK + (size_t)GN * GK;
    if (ws_size < need) return;  // clean bail -> validation failure, not a crash

    float* scales    = (float*)d_ws;
    float* partial   = (float*)d_ws + 4;
    signed char* xq  = (signed char*)d_ws + 4096;
    signed char* wq  = xq + (size_t)GM * GK;

    absmax_kernel<<<XBLK + WBLK, 256, 0, stream>>>(
        (const float4*)x, (const float4*)w, partial);
    scale_kernel<<<1, 256, 0, stream>>>(partial, scales);
    quant_kernel<<<QXBLK + QWBLK, 256, 0, stream>>>(
        (const float4*)x, (const float4*)w, scales, (char4*)xq, (char4*)wq);
    gemm_kernel<<<(GM / 128) * (GN / 128), 256, 0, stream>>>(
        xq, wq, bias, scales, out);
}